// Round 22
// baseline (451.479 us; speedup 1.0000x reference)
//
#include <hip/hip_runtime.h>
#include <hip/hip_fp16.h>

// N=100000 nodes, E=1000000 edges, D_IN=16, H=2, C=64.
// 3x (GAT -> BN -> ReLU), then MLP head -> (logits, value) concat in d_out.
// R40 == R38 resubmit #2 (R20/R21 benches were container-level infra
// failures; full bounds re-audit found no OOB/hang — all regions exact-fit).
// R38 = R37 (430.4us best) + stats slices made WAVE-private. R37's fused
// epilogue had a __syncthreads before the block-slice store -> block gated
// on slowest wave (max-of-16 Poisson tax, +3.5us vs R35's barrier-free
// aggregate). Now each wave stores its own complete 4-node sums (lanes 0-7
// hold them after shfl_xor(16/32)) to stats[(block*4+wv)*128] — no LDS, no
// barrier; waves retire independently. stats 3.2->12.8MB (+1.5us BW);
// bn_reduce1 widened to 256 blocks over 25000 slices. Also: bcnt memset
// folded into transpose_ws (one fewer dispatch).
// Kept: R37 2-stage reduction (R36's 1-block finalize was 211us), no
// atomics (R19/R22) / no fences (R27), R31 MFMA-score projection + wTg,
// R24 aggregate loop, fp16 bufB/hb (fp8 failed R33), NT stores, R29 mlp.

__device__ __forceinline__ float leaky(float x) { return x > 0.f ? x : 0.2f * x; }

typedef float f32x4 __attribute__((ext_vector_type(4)));
typedef _Float16 f16x8 __attribute__((ext_vector_type(8)));
typedef unsigned int u32x4 __attribute__((ext_vector_type(4)));

#define BCAP 4096  // max edges per 256-dst bucket (mean ~2560)

// ---------------- CSR build ----------------
__global__ void bucket_hist(const int* __restrict__ dst, int* __restrict__ bcnt, int E) {
  __shared__ int cnt[512];
  int t = threadIdx.x;
  cnt[t] = 0; cnt[t + 256] = 0;
  __syncthreads();
  for (int e = blockIdx.x * blockDim.x + t; e < E; e += gridDim.x * blockDim.x)
    atomicAdd(&cnt[dst[e] >> 8], 1);
  __syncthreads();
  for (int i = t; i < 512; i += 256)
    if (cnt[i]) atomicAdd(&bcnt[i], cnt[i]);
}

__global__ void bucket_scan(const int* __restrict__ bcnt, int* __restrict__ boff,
                            int* __restrict__ bcur, int nbk) {
  __shared__ int temp[512];
  int t = threadIdx.x;  // 512 threads
  int v = (t < nbk) ? bcnt[t] : 0;
  temp[t] = v;
  __syncthreads();
  for (int off = 1; off < 512; off <<= 1) {
    int add = (t >= off) ? temp[t - off] : 0;
    __syncthreads();
    temp[t] += add;
    __syncthreads();
  }
  if (t < nbk) {
    int ex = temp[t] - v;
    boff[t] = ex;
    bcur[t] = ex;
  }
}

__global__ __launch_bounds__(256) void bin_scatter(
    const int* __restrict__ src, const int* __restrict__ dst,
    int* __restrict__ bcur, int2* __restrict__ ebuf, int E) {
  __shared__ int cnt[512];
  __shared__ int base[512];
  int t = threadIdx.x;
  int beg = blockIdx.x * 8192;
  int end = min(E, beg + 8192);
  cnt[t] = 0; cnt[t + 256] = 0;
  __syncthreads();
  for (int e = beg + t; e < end; e += 256)
    atomicAdd(&cnt[dst[e] >> 8], 1);
  __syncthreads();
  for (int i = t; i < 512; i += 256) {
    base[i] = cnt[i] ? atomicAdd(&bcur[i], cnt[i]) : 0;
    cnt[i] = 0;  // reuse as within-run cursor
  }
  __syncthreads();
  for (int e = beg + t; e < end; e += 256) {
    int d = dst[e];
    int bk = d >> 8;
    int off = atomicAdd(&cnt[bk], 1);
    ebuf[base[bk] + off] = make_int2(src[e], d);
  }
}

__global__ __launch_bounds__(256) void bucket_sort(
    const int2* __restrict__ ebuf, const int* __restrict__ boff,
    int* __restrict__ col, int* __restrict__ row_ptr, int E, int n, int nbk) {
  __shared__ int2 eds[BCAP];
  __shared__ int dcnt[256];
  __shared__ int dbase[256];
  __shared__ int dexcl[256];
  int b = blockIdx.x, t = threadIdx.x;
  int S = boff[b];
  int Eend = (b + 1 < nbk) ? boff[b + 1] : E;
  int cnt = min(Eend - S, BCAP);
  for (int i = t; i < cnt; i += 256) eds[i] = ebuf[S + i];
  dcnt[t] = 0;
  __syncthreads();
  for (int i = t; i < cnt; i += 256) atomicAdd(&dcnt[eds[i].y & 255], 1);
  __syncthreads();
  int v = dcnt[t];
  dbase[t] = v;
  __syncthreads();
  for (int off = 1; off < 256; off <<= 1) {
    int add = (t >= off) ? dbase[t - off] : 0;
    __syncthreads();
    dbase[t] += add;
    __syncthreads();
  }
  int excl = dbase[t] - v;
  int d = (b << 8) + t;
  if (d < n) row_ptr[d] = S + excl;
  if (b == nbk - 1 && t == 0) row_ptr[n] = E;
  dcnt[t] = 0;  // reuse as per-dst cursor
  dexcl[t] = excl;
  __syncthreads();
  for (int i = t; i < cnt; i += 256) {
    int2 e = eds[i];
    int dl = e.y & 255;
    int off = atomicAdd(&dcnt[dl], 1);
    col[S + dexcl[dl] + off] = e.x;
  }
}

// ---------------- W transpose + att precombine + bcnt zeroing (once) --------
// Per layer: wTg block [144][KE] fp16. Rows 0..127 = W^T columns; rows
// 128..131 = w_as0, w_as1, w_ad0, w_ad1 (scores are linear in A); rows
// 132..143 zero. L0: KE=32 @0; L1/L2: KE=64 @4608/@13824. 90x256 grid.
// Also zeroes bcnt[0..511] (replaces the hipMemsetAsync dispatch; the
// following bucket_hist dispatch is stream-ordered after us).
__global__ void transpose_ws(
    const float* __restrict__ W0, const float* __restrict__ W1,
    const float* __restrict__ W2,
    const float* __restrict__ as0, const float* __restrict__ ad0,
    const float* __restrict__ as1, const float* __restrict__ ad1,
    const float* __restrict__ as2, const float* __restrict__ ad2,
    __half* __restrict__ wTg, int* __restrict__ bcnt) {
  int i = blockIdx.x * 256 + threadIdx.x;
  if (i < 512) bcnt[i] = 0;
  const float *W, *as, *ad;
  int KE, K, j;
  if (i < 4608)       { W = W0; as = as0; ad = ad0; KE = 32; K = 16; j = i; }
  else if (i < 13824) { W = W1; as = as1; ad = ad1; KE = 64; K = 64; j = i - 4608; }
  else if (i < 23040) { W = W2; as = as2; ad = ad2; KE = 64; K = 64; j = i - 13824; }
  else return;
  int r = j / KE, k = j % KE;
  float v = 0.f;
  if (k < K) {
    if (r < 128) {
      v = W[k * 128 + r];
    } else if (r < 132) {
      const float* att = (r & 2) ? ad : as;
      int h = r & 1;
      float acc = 0.f;
      for (int c = 0; c < 64; c++) acc += W[k * 128 + h * 64 + c] * att[h * 64 + c];
      v = acc;
    }
  }
  wTg[i] = __float2half(v);
}

// ---------------- BN reduce stage 1: nsl wave slices -> 256 partials --------
// 256 blocks x 256 threads; block b covers slices b*2+sg, step 512.
__global__ __launch_bounds__(256) void bn_reduce1(
    const float* __restrict__ stats, float* __restrict__ part, int nsl) {
  __shared__ float red[256];
  int b = blockIdx.x, t = threadIdx.x;
  int c = t & 127, sg = t >> 7;   // 2 slice-groups per block
  float acc = 0.f;
  for (int s = b * 2 + sg; s < nsl; s += 512)
    acc += stats[(size_t)s * 128 + c];
  red[t] = acc;
  __syncthreads();
  if (t < 128) part[(size_t)b * 128 + t] = red[t] + red[t + 128];
}

// ---------------- BN finalize: reduce 256 partial slices -> scsh ------------
// 1024 threads: 8 groups x 128 channels; 32 iters/thread over 128KB.
__global__ __launch_bounds__(1024) void bn_finalize(
    const float* __restrict__ part, const float* __restrict__ g,
    const float* __restrict__ be, float* __restrict__ scsh, float inv_n) {
  __shared__ float red[1024];
  int t = threadIdx.x;
  int c = t & 127;   // 0..63 sum, 64..127 sumsq
  int grp = t >> 7;  // 0..7
  float acc = 0.f;
  for (int b = grp; b < 256; b += 8) acc += part[(size_t)b * 128 + c];
  red[t] = acc;
  __syncthreads();
  if (t < 128) {
    float s = red[t];
#pragma unroll
    for (int j = 1; j < 8; j++) s += red[t + 128 * j];
    red[t] = s;  // each t<128 reads only column t -> in-place safe
  }
  __syncthreads();
  if (t < 64) {
    float mean = red[t] * inv_n;
    float var = red[64 + t] * inv_n - mean * mean;
    float sc = rsqrtf(var + 1e-5f) * g[t];
    scsh[t] = sc;
    scsh[64 + t] = be[t] - mean * sc;
  }
}

// ---------------- GAT projection: MFMA fp16, 64 nodes x (128+4) cols --------
// h = act @ W on the matrix pipe. 4 waves; 9 col-tiles (tile 8 = score
// columns from precombined att vectors). BN=true: act is fp16 bufB (16B
// chunk staging); BN=false: act is fp32 x. wT [144][KP] from wTg via
// coalesced uint4. KP = KE+8 (conflict-free b128 frag reads). C/D layout
// (m89): col=lane&15, row=(lane>>4)*4+reg.
template <int K, bool BN>
__global__ __launch_bounds__(256) void gat_project_mfma(
    const void* __restrict__ act, const float* __restrict__ scsh,
    const __half* __restrict__ wTg,
    __half2* __restrict__ hb, float* __restrict__ as_,
    float* __restrict__ ad_, int n) {
  constexpr int KE = (K < 32) ? 32 : K;   // effective (padded) K
  constexpr int KP = KE + 8;              // LDS stride in halves
  constexpr int STAGE = 64 * KP * 2 + 144 * KP * 2;
  constexpr int HSZ = 64 * 136 * 2;
  constexpr int LDSZ = (STAGE > HSZ) ? STAGE : HSZ;
  __shared__ __align__(16) char ldsb[LDSZ];
  __half* aH = (__half*)ldsb;                      // [64][KP]
  __half* wT = (__half*)(ldsb + 64 * KP * 2);      // [144][KP]
  __half* hS = (__half*)ldsb;                      // [64][136], aliases after barrier

  int t = threadIdx.x;
  int node0 = blockIdx.x * 64;
  int rows = min(64, n - node0);

  if constexpr (BN) {
    // act = fp16 [n][64]; BN+ReLU in fp32, restore fp16; 16B chunks
    const __half* a16 = (const __half*)act;
    for (int i = t; i < 512; i += 256) {     // 64 rows x 8 chunks
      int r = i >> 3, kc = i & 7;
      uint4 hv = make_uint4(0, 0, 0, 0);
      if (r < rows) hv = *(const uint4*)(a16 + (size_t)(node0 + r) * 64 + kc * 8);
      float2 f0 = __half22float2(__builtin_bit_cast(__half2, hv.x));
      float2 f1 = __half22float2(__builtin_bit_cast(__half2, hv.y));
      float2 f2 = __half22float2(__builtin_bit_cast(__half2, hv.z));
      float2 f3 = __half22float2(__builtin_bit_cast(__half2, hv.w));
      const float* sc = &scsh[kc * 8];
      const float* sh = &scsh[64 + kc * 8];
      f0.x = fmaxf(fmaf(f0.x, sc[0], sh[0]), 0.f);
      f0.y = fmaxf(fmaf(f0.y, sc[1], sh[1]), 0.f);
      f1.x = fmaxf(fmaf(f1.x, sc[2], sh[2]), 0.f);
      f1.y = fmaxf(fmaf(f1.y, sc[3], sh[3]), 0.f);
      f2.x = fmaxf(fmaf(f2.x, sc[4], sh[4]), 0.f);
      f2.y = fmaxf(fmaf(f2.y, sc[5], sh[5]), 0.f);
      f3.x = fmaxf(fmaf(f3.x, sc[6], sh[6]), 0.f);
      f3.y = fmaxf(fmaf(f3.y, sc[7], sh[7]), 0.f);
      uint4 pk;
      pk.x = __builtin_bit_cast(unsigned, __floats2half2_rn(f0.x, f0.y));
      pk.y = __builtin_bit_cast(unsigned, __floats2half2_rn(f1.x, f1.y));
      pk.z = __builtin_bit_cast(unsigned, __floats2half2_rn(f2.x, f2.y));
      pk.w = __builtin_bit_cast(unsigned, __floats2half2_rn(f3.x, f3.y));
      *(uint4*)&aH[r * KP + kc * 8] = pk;
    }
  } else {
    // act = fp32 x [n][K]; zero-pad k>=K
    const float* a32 = (const float*)act;
    constexpr int ACH = 64 * KE / 4;
    for (int i = t; i < ACH; i += 256) {
      int r = i / (KE / 4), kc = i % (KE / 4);
      float4 v = make_float4(0.f, 0.f, 0.f, 0.f);
      if (r < rows && kc * 4 < K)
        v = *(const float4*)&a32[(size_t)(node0 + r) * K + kc * 4];
      __half2 h01 = __floats2half2_rn(v.x, v.y);
      __half2 h23 = __floats2half2_rn(v.z, v.w);
      uint2 pk = make_uint2(__builtin_bit_cast(unsigned, h01),
                            __builtin_bit_cast(unsigned, h23));
      *(uint2*)&aH[r * KP + kc * 4] = pk;
    }
  }
  // ---- stage wT: coalesced uint4 copy from pre-transposed wTg [144][KE]
  constexpr int WCH = 144 * KE / 8;   // 16B chunks
  for (int i = t; i < WCH; i += 256) {
    int c = i / (KE / 8), j = i % (KE / 8);
    *(uint4*)&wT[c * KP + j * 8] = *(const uint4*)&wTg[c * KE + j * 8];
  }
  __syncthreads();

  int w = t >> 6, l = t & 63;
  int cl = l & 15, r4 = l >> 4;
  int w16 = w * 16;

  f32x4 acc[9] = {};
#pragma unroll
  for (int ks = 0; ks < KE / 32; ks++) {
    f16x8 av = *(const f16x8*)&aH[(w16 + cl) * KP + ks * 32 + r4 * 8];
#pragma unroll
    for (int ct = 0; ct < 9; ct++) {
      f16x8 bv = *(const f16x8*)&wT[(ct * 16 + cl) * KP + ks * 32 + r4 * 8];
      acc[ct] = __builtin_amdgcn_mfma_f32_16x16x32_f16(av, bv, acc[ct], 0, 0, 0);
    }
  }

  // ---- scores: direct lane writes from tile 8 (cols 128..131)
#pragma unroll
  for (int i = 0; i < 4; i++) {
    int rloc = w16 + r4 * 4 + i;
    if (rloc < rows && cl < 4) {
      int row = node0 + rloc;
      float sv = acc[8][i];
      if (cl == 0) as_[row * 2] = sv;
      else if (cl == 1) as_[row * 2 + 1] = sv;
      else if (cl == 2) ad_[row * 2] = sv;
      else ad_[row * 2 + 1] = sv;
    }
  }

  __syncthreads();  // aH/wT dead -> reuse as hS
  // ---- C fragments -> hS fp16 [64][136]
#pragma unroll
  for (int ct = 0; ct < 8; ct++)
#pragma unroll
    for (int i = 0; i < 4; i++)
      hS[(w16 + r4 * 4 + i) * 136 + ct * 16 + cl] = __float2half(acc[ct][i]);
  __syncthreads();
  // ---- hS -> hb, coalesced 16B chunks (256B per node row)
#pragma unroll
  for (int it = 0; it < 4; it++) {
    int flat = t + it * 256;
    int nd = flat >> 4, ch = flat & 15;
    if (nd < rows)
      *(uint4*)((char*)hb + (((size_t)(node0 + nd)) << 8) + (ch << 4)) =
          *(const uint4*)((const char*)hS + nd * 272 + (ch << 4));
  }
}

// ---------------- GAT aggregation + fused BN stats (wave-private) -----------
// 16 lanes/node, 4 nodes/wave (R24 loop). Stats epilogue: shfl_xor(16/32)
// leaves the wave's complete 4-node sums in lanes 0-7; stored straight to
// the WAVE-private slice stats[(block*4+wv)*128] — no LDS, NO BARRIER,
// no atomics, no fences. hb fp16 gathers; bufB fp16 NT stores.
__device__ __forceinline__ void fma8(float* a, float my, uint4 raw) {
  float2 f;
  f = __half22float2(__builtin_bit_cast(__half2, raw.x)); a[0] = fmaf(my, f.x, a[0]); a[1] = fmaf(my, f.y, a[1]);
  f = __half22float2(__builtin_bit_cast(__half2, raw.y)); a[2] = fmaf(my, f.x, a[2]); a[3] = fmaf(my, f.y, a[3]);
  f = __half22float2(__builtin_bit_cast(__half2, raw.z)); a[4] = fmaf(my, f.x, a[4]); a[5] = fmaf(my, f.y, a[5]);
  f = __half22float2(__builtin_bit_cast(__half2, raw.w)); a[6] = fmaf(my, f.x, a[6]); a[7] = fmaf(my, f.y, a[7]);
}

__global__ __launch_bounds__(256) void gat_aggregate(
    const __half2* __restrict__ hb,
    const float* __restrict__ as_, const float* __restrict__ ad_,
    const int* __restrict__ row_ptr, const int* __restrict__ col,
    const float* __restrict__ bias, __half* __restrict__ out,
    float* __restrict__ stats, int n) {
  int t = threadIdx.x;
  int wv = t >> 6;
  int lane = t & 63;
  int g = lane >> 4, q = lane & 15;
  int d = blockIdx.x * 16 + wv * 4 + g;
  bool active = d < n;
  int hidx = (q >= 8) ? 1 : 0;
  const uint4* hb4 = (const uint4*)hb;   // 16 uint4 per node (256 B)

  float a[8] = {};
  float dpart = 0.f;

  if (active) {
    int beg = row_ptr[d], end = row_ptr[d + 1];
    float ad_my = ad_[d * 2 + hidx];

    // self-loop (not in CSR)
    float asv = as_[d * 2 + hidx];
    float my = __expf(leaky(asv + ad_my));
    uint4 raw = hb4[(size_t)d * 16 + q];
    fma8(a, my, raw);
    dpart = my;

    int k = beg;
    for (; k + 3 < end; k += 4) {
      int s0 = col[k], s1 = col[k + 1], s2 = col[k + 2], s3 = col[k + 3];
      float e0 = as_[s0 * 2 + hidx];
      float e1 = as_[s1 * 2 + hidx];
      float e2 = as_[s2 * 2 + hidx];
      float e3 = as_[s3 * 2 + hidx];
      uint4 r0 = hb4[(size_t)s0 * 16 + q];
      uint4 r1 = hb4[(size_t)s1 * 16 + q];
      uint4 r2 = hb4[(size_t)s2 * 16 + q];
      uint4 r3 = hb4[(size_t)s3 * 16 + q];
      float m0 = __expf(leaky(e0 + ad_my));
      float m1 = __expf(leaky(e1 + ad_my));
      float m2 = __expf(leaky(e2 + ad_my));
      float m3 = __expf(leaky(e3 + ad_my));
      fma8(a, m0, r0); fma8(a, m1, r1); fma8(a, m2, r2); fma8(a, m3, r3);
      dpart += m0 + m1 + m2 + m3;
    }
    for (; k < end; k++) {  // tail 0..3
      int s = col[k];
      float e = as_[s * 2 + hidx];
      uint4 r = hb4[(size_t)s * 16 + q];
      float m = __expf(leaky(e + ad_my));
      fma8(a, m, r);
      dpart += m;
    }
  }

  // head swap within the 16-lane group (serves all 4 nodes of the wave)
  float b[8];
#pragma unroll
  for (int i = 0; i < 8; i++) b[i] = __shfl_xor(a[i], 8);
  float denO = __shfl_xor(dpart, 8);

  float o[8] = {0.f, 0.f, 0.f, 0.f, 0.f, 0.f, 0.f, 0.f};
  if (active && q < 8) {  // channels 8q..8q+7
    float rr0 = 1.f / (dpart + 1e-16f), rr1 = 1.f / (denO + 1e-16f);
    float4 bl = *(const float4*)&bias[q * 8];
    float4 bh = *(const float4*)&bias[q * 8 + 4];
    o[0] = 0.5f * (a[0] * rr0 + b[0] * rr1) + bl.x;
    o[1] = 0.5f * (a[1] * rr0 + b[1] * rr1) + bl.y;
    o[2] = 0.5f * (a[2] * rr0 + b[2] * rr1) + bl.z;
    o[3] = 0.5f * (a[3] * rr0 + b[3] * rr1) + bl.w;
    o[4] = 0.5f * (a[4] * rr0 + b[4] * rr1) + bh.x;
    o[5] = 0.5f * (a[5] * rr0 + b[5] * rr1) + bh.y;
    o[6] = 0.5f * (a[6] * rr0 + b[6] * rr1) + bh.z;
    o[7] = 0.5f * (a[7] * rr0 + b[7] * rr1) + bh.w;
    u32x4 pk;
    pk.x = __builtin_bit_cast(unsigned, __floats2half2_rn(o[0], o[1]));
    pk.y = __builtin_bit_cast(unsigned, __floats2half2_rn(o[2], o[3]));
    pk.z = __builtin_bit_cast(unsigned, __floats2half2_rn(o[4], o[5]));
    pk.w = __builtin_bit_cast(unsigned, __floats2half2_rn(o[6], o[7]));
    u32x4* outp = (u32x4*)((char*)out + (((size_t)d) << 7) + (q << 4));
    __builtin_nontemporal_store(pk, outp);
  }

  // ---- fused BN stats: shfl_xor(16/32) sums the wave's 4 nodes (q>=8 and
  // inactive lanes carry zeros); lanes 0-7 store the wave-private slice.
  float so[8], sq[8];
#pragma unroll
  for (int j = 0; j < 8; j++) {
    float v = o[j], v2 = o[j] * o[j];
    v += __shfl_xor(v, 16); v2 += __shfl_xor(v2, 16);
    v += __shfl_xor(v, 32); v2 += __shfl_xor(v2, 32);
    so[j] = v; sq[j] = v2;
  }
  if (lane < 8) {
    float* sp = &stats[((size_t)blockIdx.x * 4 + wv) * 128 + lane * 8];
    *(float4*)(sp)      = make_float4(so[0], so[1], so[2], so[3]);
    *(float4*)(sp + 4)  = make_float4(so[4], so[5], so[6], so[7]);
    *(float4*)(sp + 64) = make_float4(sq[0], sq[1], sq[2], sq[3]);
    *(float4*)(sp + 68) = make_float4(sq[4], sq[5], sq[6], sq[7]);
  }
}

// ---------------- MLP head: fused tiled GEMM (64 nodes / block) --------------
// a1 staging applies BN(layer3 scsh)+ReLU to the fp16 aggregate output.
// LDS 37.1 KB: GEMM1 output written IN-PLACE over a1, w2 over w1.
__global__ __launch_bounds__(256) void mlp_head_tiled(
    const __half* __restrict__ h3raw, const float* __restrict__ scsh,
    const float* __restrict__ x,
    const float* __restrict__ mW1, const float* __restrict__ mb1,
    const float* __restrict__ mW2, const float* __restrict__ mb2,
    const float* __restrict__ pW, const float* __restrict__ pb,
    const float* __restrict__ vW, const float* __restrict__ vb,
    float* __restrict__ out, int n) {
  __shared__ float lds[9280];
  float* a1  = lds;           // 64*68 = 4352; GEMM1 input, then GEMM1 output
  float* ctx = lds + 4352;    // 64*8  = 512
  float* w1  = lds + 4864;    // 69*64 = 4416; then w2 (64*64 = 4096)

  int t = threadIdx.x;
  int node0 = blockIdx.x * 64;
  int rows = min(64, n - node0);

#pragma unroll
  for (int i = 0; i < 2; i++) {
    int flat = t + i * 256;           // 64 rows x 8 chunks of 8 halves
    int r = flat >> 3, kc = flat & 7;
    uint4 hv = make_uint4(0, 0, 0, 0);
    if (r < rows) hv = *(const uint4*)(h3raw + (size_t)(node0 + r) * 64 + kc * 8);
    float2 f0 = __half22float2(__builtin_bit_cast(__half2, hv.x));
    float2 f1 = __half22float2(__builtin_bit_cast(__half2, hv.y));
    float2 f2 = __half22float2(__builtin_bit_cast(__half2, hv.z));
    float2 f3 = __half22float2(__builtin_bit_cast(__half2, hv.w));
    const float* sc = &scsh[kc * 8];
    const float* sh = &scsh[64 + kc * 8];
    float4 va, vb2;
    va.x = fmaxf(fmaf(f0.x, sc[0], sh[0]), 0.f);
    va.y = fmaxf(fmaf(f0.y, sc[1], sh[1]), 0.f);
    va.z = fmaxf(fmaf(f1.x, sc[2], sh[2]), 0.f);
    va.w = fmaxf(fmaf(f1.y, sc[3], sh[3]), 0.f);
    vb2.x = fmaxf(fmaf(f2.x, sc[4], sh[4]), 0.f);
    vb2.y = fmaxf(fmaf(f2.y, sc[5], sh[5]), 0.f);
    vb2.z = fmaxf(fmaf(f3.x, sc[6], sh[6]), 0.f);
    vb2.w = fmaxf(fmaf(f3.y, sc[7], sh[7]), 0.f);
    *(float4*)&a1[r * 68 + kc * 8] = va;
    *(float4*)&a1[r * 68 + kc * 8 + 4] = vb2;
  }
  for (int i = t; i < 320; i += 256) {
    int r = i / 5, j = i % 5;
    ctx[r * 8 + j] = (r < rows) ? x[(size_t)(node0 + r) * 16 + 9 + j] : 0.f;
  }
#pragma unroll
  for (int i = 0; i < 5; i++) {
    int flat = t + i * 256;
    if (flat < 1104) *(float4*)&w1[flat * 4] = *(const float4*)&mW1[flat * 4];
  }
  __syncthreads();

  int tc = t & 15, tr = t >> 4;
  int c0 = tc * 4, r0 = tr * 4;

  float acc[4][4] = {};
  for (int k = 0; k < 64; k += 4) {
    float4 av[4], wv[4];
#pragma unroll
    for (int i = 0; i < 4; i++) av[i] = *(const float4*)&a1[(r0 + i) * 68 + k];
#pragma unroll
    for (int j = 0; j < 4; j++) wv[j] = *(const float4*)&w1[(k + j) * 64 + c0];
#pragma unroll
    for (int i = 0; i < 4; i++) {
      const float* ai = (const float*)&av[i];
#pragma unroll
      for (int kk = 0; kk < 4; kk++) {
        const float* wr = (const float*)&wv[kk];
        acc[i][0] = fmaf(ai[kk], wr[0], acc[i][0]);
        acc[i][1] = fmaf(ai[kk], wr[1], acc[i][1]);
        acc[i][2] = fmaf(ai[kk], wr[2], acc[i][2]);
        acc[i][3] = fmaf(ai[kk], wr[3], acc[i][3]);
      }
    }
  }
#pragma unroll
  for (int k = 64; k < 69; k++) {
    float4 wv = *(const float4*)&w1[k * 64 + c0];
    const float* wr = (const float*)&wv;
#pragma unroll
    for (int i = 0; i < 4; i++) {
      float a = ctx[(r0 + i) * 8 + (k - 64)];
      acc[i][0] = fmaf(a, wr[0], acc[i][0]);
      acc[i][1] = fmaf(a, wr[1], acc[i][1]);
      acc[i][2] = fmaf(a, wr[2], acc[i][2]);
      acc[i][3] = fmaf(a, wr[3], acc[i][3]);
    }
  }
  float b1v0 = mb1[c0], b1v1 = mb1[c0 + 1], b1v2 = mb1[c0 + 2], b1v3 = mb1[c0 + 3];
  float4 t1v[4];
#pragma unroll
  for (int i = 0; i < 4; i++) {
    t1v[i].x = fmaxf(acc[i][0] + b1v0, 0.f);
    t1v[i].y = fmaxf(acc[i][1] + b1v1, 0.f);
    t1v[i].z = fmaxf(acc[i][2] + b1v2, 0.f);
    t1v[i].w = fmaxf(acc[i][3] + b1v3, 0.f);
  }
  __syncthreads();  // all GEMM1 reads of a1/w1 done -> regions reusable

  // GEMM1 output in-place over a1; w2 over w1
#pragma unroll
  for (int i = 0; i < 4; i++)
    *(float4*)&a1[(r0 + i) * 68 + c0] = t1v[i];
#pragma unroll
  for (int i = 0; i < 4; i++) {
    int flat = t + i * 256;
    *(float4*)&w1[flat * 4] = *(const float4*)&mW2[flat * 4];
  }
  __syncthreads();

  float acc2[4][4] = {};
  for (int k = 0; k < 64; k += 4) {
    float4 av[4], wv[4];
#pragma unroll
    for (int i = 0; i < 4; i++) av[i] = *(const float4*)&a1[(r0 + i) * 68 + k];
#pragma unroll
    for (int j = 0; j < 4; j++) wv[j] = *(const float4*)&w1[(k + j) * 64 + c0];
#pragma unroll
    for (int i = 0; i < 4; i++) {
      const float* ai = (const float*)&av[i];
#pragma unroll
      for (int kk = 0; kk < 4; kk++) {
        const float* wr = (const float*)&wv[kk];
        acc2[i][0] = fmaf(ai[kk], wr[0], acc2[i][0]);
        acc2[i][1] = fmaf(ai[kk], wr[1], acc2[i][1]);
        acc2[i][2] = fmaf(ai[kk], wr[2], acc2[i][2]);
        acc2[i][3] = fmaf(ai[kk], wr[3], acc2[i][3]);
      }
    }
  }

  float b2v[4], pwv[4], vwv[4];
#pragma unroll
  for (int j = 0; j < 4; j++) {
    b2v[j] = mb2[c0 + j];
    pwv[j] = pW[c0 + j];
    vwv[j] = vW[c0 + j];
  }
  float p[4], v[4];
#pragma unroll
  for (int i = 0; i < 4; i++) {
    float ps = 0.f, vs = 0.f;
#pragma unroll
    for (int j = 0; j < 4; j++) {
      float u = acc2[i][j] + b2v[j];
      ps = fmaf(u, pwv[j], ps);
      vs = fmaf(u, vwv[j], vs);
    }
    p[i] = ps; v[i] = vs;
  }
#pragma unroll
  for (int off = 1; off < 16; off <<= 1) {
#pragma unroll
    for (int i = 0; i < 4; i++) {
      p[i] += __shfl_xor(p[i], off);
      v[i] += __shfl_xor(v[i], off);
    }
  }
  if (tc == 0) {
    float pbs = pb[0], vbs = vb[0];
#pragma unroll
    for (int i = 0; i < 4; i++) {
      int r = r0 + i;
      if (r < rows) {
        out[node0 + r] = p[i] + pbs;
        out[n + node0 + r] = v[i] + vbs;
      }
    }
  }
}

extern "C" void kernel_launch(void* const* d_in, const int* in_sizes, int n_in,
                              void* d_out, int out_size, void* d_ws, size_t ws_size,
                              hipStream_t stream) {
  const float* x = (const float*)d_in[0];
  const int* ei = (const int*)d_in[1];
  const float* W[3]  = {(const float*)d_in[2],  (const float*)d_in[8],  (const float*)d_in[14]};
  const float* AS[3] = {(const float*)d_in[3],  (const float*)d_in[9],  (const float*)d_in[15]};
  const float* AD[3] = {(const float*)d_in[4],  (const float*)d_in[10], (const float*)d_in[16]};
  const float* B[3]  = {(const float*)d_in[5],  (const float*)d_in[11], (const float*)d_in[17]};
  const float* G[3]  = {(const float*)d_in[6],  (const float*)d_in[12], (const float*)d_in[18]};
  const float* BE[3] = {(const float*)d_in[7],  (const float*)d_in[13], (const float*)d_in[19]};
  const float* mW1 = (const float*)d_in[20];
  const float* mb1 = (const float*)d_in[21];
  const float* mW2 = (const float*)d_in[22];
  const float* mb2 = (const float*)d_in[23];
  const float* pW  = (const float*)d_in[24];
  const float* pb  = (const float*)d_in[25];
  const float* vW  = (const float*)d_in[26];
  const float* vb  = (const float*)d_in[27];

  const int N = in_sizes[0] / 16;
  const int E = in_sizes[1] / 2;
  const int* srcp = ei;
  const int* dstp = ei + E;

  const int agg_blocks = (N + 15) / 16;  // 4 nodes/wave, 4 waves/block
  const int nslices = agg_blocks * 4;    // wave-private stats slices

  // workspace carve-up (~65 MB; bufB region sized to its used half)
  float* bufB  = (float*)d_ws;               // N*32 floats = N*64 halves (fp16)
  float* hbuf  = bufB + (size_t)N * 32;      // N*64 half2 region (fp16 hb)
  float* as_   = hbuf + (size_t)N * 64;      // N*2
  float* ad_   = as_ + (size_t)N * 2;        // N*2
  float* stats = ad_ + (size_t)N * 2;        // nslices*128 (wave slices)
  float* part  = stats + (size_t)nslices * 128;  // 256*128 partials
  float* scsh  = part + 256 * 128;           // 128
  __half* wTg  = (__half*)(scsh + 128);      // 23040 halves (3 x [144][KE])
  int* row_ptr = (int*)(wTg + 23040);        // N+1
  int* bcnt    = row_ptr + (N + 1);          // 512
  int* boff    = bcnt + 512;                 // 512
  int* bcur    = boff + 512;                 // 512
  int* col     = bcur + 512;                 // E ints (sorted CSR, src only)
  int2* ebuf   = (int2*)(col + E);           // E int2 (staging)
  __half2* hb  = (__half2*)hbuf;
  __half* bufH = (__half*)bufB;
  const __half* wTgL[3] = {wTg, wTg + 4608, wTg + 13824};

  const int nbk = (N + 255) >> 8;
  const float inv_n = 1.0f / (float)N;

  // ---- W transposes + att precombine + bcnt zeroing (once) + CSR build
  transpose_ws<<<90, 256, 0, stream>>>(W[0], W[1], W[2], AS[0], AD[0],
                                       AS[1], AD[1], AS[2], AD[2], wTg, bcnt);
  bucket_hist<<<256, 256, 0, stream>>>(dstp, bcnt, E);
  bucket_scan<<<1, 512, 0, stream>>>(bcnt, boff, bcur, nbk);
  bin_scatter<<<(E + 8191) / 8192, 256, 0, stream>>>(srcp, dstp, bcur, ebuf, E);
  bucket_sort<<<nbk, 256, 0, stream>>>(ebuf, boff, col, row_ptr, E, N, nbk);

  const int tiles = (N + 63) / 64;

  // ---- 3 GAT layers (BN+ReLU fused into the next consumer via scsh;
  //      BN stats fused into aggregate; 2-stage parallel slice reduction)
  for (int l = 0; l < 3; l++) {
    if (l == 0)
      gat_project_mfma<16, false><<<tiles, 256, 0, stream>>>(x, scsh, wTgL[l],
                                                             hb, as_, ad_, N);
    else
      gat_project_mfma<64, true><<<tiles, 256, 0, stream>>>(bufH, scsh, wTgL[l],
                                                            hb, as_, ad_, N);
    gat_aggregate<<<agg_blocks, 256, 0, stream>>>(hb, as_, ad_, row_ptr, col,
                                                  B[l], bufH, stats, N);
    bn_reduce1<<<256, 256, 0, stream>>>(stats, part, nslices);
    bn_finalize<<<1, 1024, 0, stream>>>(part, G[l], BE[l], scsh, inv_n);
  }

  // ---- MLP head -> (logits, value); applies layer-3 BN+ReLU to bufH
  mlp_head_tiled<<<tiles, 256, 0, stream>>>(bufH, scsh, x, mW1, mb1, mW2, mb2,
                                            pW, pb, vW, vb, (float*)d_out, N);
}

// Round 23
// 426.878 us; speedup vs baseline: 1.0576x; 1.0576x over previous
//
#include <hip/hip_runtime.h>
#include <hip/hip_fp16.h>

// N=100000 nodes, E=1000000 edges, D_IN=16, H=2, C=64.
// 3x (GAT -> BN -> ReLU), then MLP head -> (logits, value) concat in d_out.
// R41 == R37 verbatim (verified 430.4us best). R38/R40 post-mortem: making
// stats slices wave-private did NOT speed the aggregate (48.4us with AND
// without the barrier — the epilogue shfl/store work is the cost, not the
// barrier) and 4x'd stats traffic -> 451.5us. R37 strictly dominates.
// R37 = fused BN stats in the aggregate epilogue via PRIVATE PER-BLOCK
// slices (no atomics — R19/R22's 3.2M cross-XCD RMW killer; no fences —
// R27's L2-writeback killer) + 2-STAGE reduction (R36's 1-block finalize
// read 3.2MB on one CU = 211us; stage1 spreads it over 128 CUs).
// Kept: R31 MFMA-score projection (scores on matrix pipe via precombined
// att vectors) + hoisted wTg transpose, R24 aggregate loop (16 lanes/node,
// 4 nodes/wave, 4-deep), fp16 bufB/hb (fp8 failed correctness R33), NT
// stores, R29 slim mlp (37KB LDS), R17 CSR build.

__device__ __forceinline__ float leaky(float x) { return x > 0.f ? x : 0.2f * x; }

typedef float f32x4 __attribute__((ext_vector_type(4)));
typedef _Float16 f16x8 __attribute__((ext_vector_type(8)));
typedef unsigned int u32x4 __attribute__((ext_vector_type(4)));

#define BCAP 4096  // max edges per 256-dst bucket (mean ~2560)

// ---------------- CSR build ----------------
__global__ void bucket_hist(const int* __restrict__ dst, int* __restrict__ bcnt, int E) {
  __shared__ int cnt[512];
  int t = threadIdx.x;
  cnt[t] = 0; cnt[t + 256] = 0;
  __syncthreads();
  for (int e = blockIdx.x * blockDim.x + t; e < E; e += gridDim.x * blockDim.x)
    atomicAdd(&cnt[dst[e] >> 8], 1);
  __syncthreads();
  for (int i = t; i < 512; i += 256)
    if (cnt[i]) atomicAdd(&bcnt[i], cnt[i]);
}

__global__ void bucket_scan(const int* __restrict__ bcnt, int* __restrict__ boff,
                            int* __restrict__ bcur, int nbk) {
  __shared__ int temp[512];
  int t = threadIdx.x;  // 512 threads
  int v = (t < nbk) ? bcnt[t] : 0;
  temp[t] = v;
  __syncthreads();
  for (int off = 1; off < 512; off <<= 1) {
    int add = (t >= off) ? temp[t - off] : 0;
    __syncthreads();
    temp[t] += add;
    __syncthreads();
  }
  if (t < nbk) {
    int ex = temp[t] - v;
    boff[t] = ex;
    bcur[t] = ex;
  }
}

__global__ __launch_bounds__(256) void bin_scatter(
    const int* __restrict__ src, const int* __restrict__ dst,
    int* __restrict__ bcur, int2* __restrict__ ebuf, int E) {
  __shared__ int cnt[512];
  __shared__ int base[512];
  int t = threadIdx.x;
  int beg = blockIdx.x * 8192;
  int end = min(E, beg + 8192);
  cnt[t] = 0; cnt[t + 256] = 0;
  __syncthreads();
  for (int e = beg + t; e < end; e += 256)
    atomicAdd(&cnt[dst[e] >> 8], 1);
  __syncthreads();
  for (int i = t; i < 512; i += 256) {
    base[i] = cnt[i] ? atomicAdd(&bcur[i], cnt[i]) : 0;
    cnt[i] = 0;  // reuse as within-run cursor
  }
  __syncthreads();
  for (int e = beg + t; e < end; e += 256) {
    int d = dst[e];
    int bk = d >> 8;
    int off = atomicAdd(&cnt[bk], 1);
    ebuf[base[bk] + off] = make_int2(src[e], d);
  }
}

__global__ __launch_bounds__(256) void bucket_sort(
    const int2* __restrict__ ebuf, const int* __restrict__ boff,
    int* __restrict__ col, int* __restrict__ row_ptr, int E, int n, int nbk) {
  __shared__ int2 eds[BCAP];
  __shared__ int dcnt[256];
  __shared__ int dbase[256];
  __shared__ int dexcl[256];
  int b = blockIdx.x, t = threadIdx.x;
  int S = boff[b];
  int Eend = (b + 1 < nbk) ? boff[b + 1] : E;
  int cnt = min(Eend - S, BCAP);
  for (int i = t; i < cnt; i += 256) eds[i] = ebuf[S + i];
  dcnt[t] = 0;
  __syncthreads();
  for (int i = t; i < cnt; i += 256) atomicAdd(&dcnt[eds[i].y & 255], 1);
  __syncthreads();
  int v = dcnt[t];
  dbase[t] = v;
  __syncthreads();
  for (int off = 1; off < 256; off <<= 1) {
    int add = (t >= off) ? dbase[t - off] : 0;
    __syncthreads();
    dbase[t] += add;
    __syncthreads();
  }
  int excl = dbase[t] - v;
  int d = (b << 8) + t;
  if (d < n) row_ptr[d] = S + excl;
  if (b == nbk - 1 && t == 0) row_ptr[n] = E;
  dcnt[t] = 0;  // reuse as per-dst cursor
  dexcl[t] = excl;
  __syncthreads();
  for (int i = t; i < cnt; i += 256) {
    int2 e = eds[i];
    int dl = e.y & 255;
    int off = atomicAdd(&dcnt[dl], 1);
    col[S + dexcl[dl] + off] = e.x;
  }
}

// ---------------- W transpose + att-vector precombine (once) ----------------
// Per layer: wTg block [144][KE] fp16. Rows 0..127 = W^T columns; rows
// 128..131 = w_as0, w_as1, w_ad0, w_ad1 (scores are linear in A); rows
// 132..143 zero. L0: KE=32 @0; L1/L2: KE=64 @4608/@13824. 90x256 grid.
__global__ void transpose_ws(
    const float* __restrict__ W0, const float* __restrict__ W1,
    const float* __restrict__ W2,
    const float* __restrict__ as0, const float* __restrict__ ad0,
    const float* __restrict__ as1, const float* __restrict__ ad1,
    const float* __restrict__ as2, const float* __restrict__ ad2,
    __half* __restrict__ wTg) {
  int i = blockIdx.x * 256 + threadIdx.x;
  const float *W, *as, *ad;
  int KE, K, j;
  if (i < 4608)       { W = W0; as = as0; ad = ad0; KE = 32; K = 16; j = i; }
  else if (i < 13824) { W = W1; as = as1; ad = ad1; KE = 64; K = 64; j = i - 4608; }
  else if (i < 23040) { W = W2; as = as2; ad = ad2; KE = 64; K = 64; j = i - 13824; }
  else return;
  int r = j / KE, k = j % KE;
  float v = 0.f;
  if (k < K) {
    if (r < 128) {
      v = W[k * 128 + r];
    } else if (r < 132) {
      const float* att = (r & 2) ? ad : as;
      int h = r & 1;
      float acc = 0.f;
      for (int c = 0; c < 64; c++) acc += W[k * 128 + h * 64 + c] * att[h * 64 + c];
      v = acc;
    }
  }
  wTg[i] = __float2half(v);
}

// ---------------- BN reduce stage 1: nsl private slices -> 128 partials -----
// 128 blocks x 256 threads; block b covers slices b*2+sg, step 256.
// Coalesced scalar loads (128 threads span 512B of a slice; slices adjacent).
__global__ __launch_bounds__(256) void bn_reduce1(
    const float* __restrict__ stats, float* __restrict__ part, int nsl) {
  __shared__ float red[256];
  int b = blockIdx.x, t = threadIdx.x;
  int c = t & 127, sg = t >> 7;   // 2 slice-groups per block
  float acc = 0.f;
  for (int s = b * 2 + sg; s < nsl; s += 256)
    acc += stats[(size_t)s * 128 + c];
  red[t] = acc;
  __syncthreads();
  if (t < 128) part[(size_t)b * 128 + t] = red[t] + red[t + 128];
}

// ---------------- BN finalize: reduce 128 partial slices -> scsh ------------
// 1024 threads: 8 groups x 128 channels; 16 iters/thread over 64KB.
__global__ __launch_bounds__(1024) void bn_finalize(
    const float* __restrict__ part, const float* __restrict__ g,
    const float* __restrict__ be, float* __restrict__ scsh, float inv_n) {
  __shared__ float red[1024];
  int t = threadIdx.x;
  int c = t & 127;   // 0..63 sum, 64..127 sumsq
  int grp = t >> 7;  // 0..7
  float acc = 0.f;
  for (int b = grp; b < 128; b += 8) acc += part[(size_t)b * 128 + c];
  red[t] = acc;
  __syncthreads();
  if (t < 128) {
    float s = red[t];
#pragma unroll
    for (int j = 1; j < 8; j++) s += red[t + 128 * j];
    red[t] = s;  // each t<128 reads only column t -> in-place safe
  }
  __syncthreads();
  if (t < 64) {
    float mean = red[t] * inv_n;
    float var = red[64 + t] * inv_n - mean * mean;
    float sc = rsqrtf(var + 1e-5f) * g[t];
    scsh[t] = sc;
    scsh[64 + t] = be[t] - mean * sc;
  }
}

// ---------------- GAT projection: MFMA fp16, 64 nodes x (128+4) cols --------
// h = act @ W on the matrix pipe. 4 waves; 9 col-tiles (tile 8 = score
// columns from precombined att vectors). BN=true: act is fp16 bufB (16B
// chunk staging); BN=false: act is fp32 x. wT [144][KP] from wTg via
// coalesced uint4. KP = KE+8 (conflict-free b128 frag reads). C/D layout
// (m89): col=lane&15, row=(lane>>4)*4+reg.
template <int K, bool BN>
__global__ __launch_bounds__(256) void gat_project_mfma(
    const void* __restrict__ act, const float* __restrict__ scsh,
    const __half* __restrict__ wTg,
    __half2* __restrict__ hb, float* __restrict__ as_,
    float* __restrict__ ad_, int n) {
  constexpr int KE = (K < 32) ? 32 : K;   // effective (padded) K
  constexpr int KP = KE + 8;              // LDS stride in halves
  constexpr int STAGE = 64 * KP * 2 + 144 * KP * 2;
  constexpr int HSZ = 64 * 136 * 2;
  constexpr int LDSZ = (STAGE > HSZ) ? STAGE : HSZ;
  __shared__ __align__(16) char ldsb[LDSZ];
  __half* aH = (__half*)ldsb;                      // [64][KP]
  __half* wT = (__half*)(ldsb + 64 * KP * 2);      // [144][KP]
  __half* hS = (__half*)ldsb;                      // [64][136], aliases after barrier

  int t = threadIdx.x;
  int node0 = blockIdx.x * 64;
  int rows = min(64, n - node0);

  if constexpr (BN) {
    // act = fp16 [n][64]; BN+ReLU in fp32, restore fp16; 16B chunks
    const __half* a16 = (const __half*)act;
    for (int i = t; i < 512; i += 256) {     // 64 rows x 8 chunks
      int r = i >> 3, kc = i & 7;
      uint4 hv = make_uint4(0, 0, 0, 0);
      if (r < rows) hv = *(const uint4*)(a16 + (size_t)(node0 + r) * 64 + kc * 8);
      float2 f0 = __half22float2(__builtin_bit_cast(__half2, hv.x));
      float2 f1 = __half22float2(__builtin_bit_cast(__half2, hv.y));
      float2 f2 = __half22float2(__builtin_bit_cast(__half2, hv.z));
      float2 f3 = __half22float2(__builtin_bit_cast(__half2, hv.w));
      const float* sc = &scsh[kc * 8];
      const float* sh = &scsh[64 + kc * 8];
      f0.x = fmaxf(fmaf(f0.x, sc[0], sh[0]), 0.f);
      f0.y = fmaxf(fmaf(f0.y, sc[1], sh[1]), 0.f);
      f1.x = fmaxf(fmaf(f1.x, sc[2], sh[2]), 0.f);
      f1.y = fmaxf(fmaf(f1.y, sc[3], sh[3]), 0.f);
      f2.x = fmaxf(fmaf(f2.x, sc[4], sh[4]), 0.f);
      f2.y = fmaxf(fmaf(f2.y, sc[5], sh[5]), 0.f);
      f3.x = fmaxf(fmaf(f3.x, sc[6], sh[6]), 0.f);
      f3.y = fmaxf(fmaf(f3.y, sc[7], sh[7]), 0.f);
      uint4 pk;
      pk.x = __builtin_bit_cast(unsigned, __floats2half2_rn(f0.x, f0.y));
      pk.y = __builtin_bit_cast(unsigned, __floats2half2_rn(f1.x, f1.y));
      pk.z = __builtin_bit_cast(unsigned, __floats2half2_rn(f2.x, f2.y));
      pk.w = __builtin_bit_cast(unsigned, __floats2half2_rn(f3.x, f3.y));
      *(uint4*)&aH[r * KP + kc * 8] = pk;
    }
  } else {
    // act = fp32 x [n][K]; zero-pad k>=K
    const float* a32 = (const float*)act;
    constexpr int ACH = 64 * KE / 4;
    for (int i = t; i < ACH; i += 256) {
      int r = i / (KE / 4), kc = i % (KE / 4);
      float4 v = make_float4(0.f, 0.f, 0.f, 0.f);
      if (r < rows && kc * 4 < K)
        v = *(const float4*)&a32[(size_t)(node0 + r) * K + kc * 4];
      __half2 h01 = __floats2half2_rn(v.x, v.y);
      __half2 h23 = __floats2half2_rn(v.z, v.w);
      uint2 pk = make_uint2(__builtin_bit_cast(unsigned, h01),
                            __builtin_bit_cast(unsigned, h23));
      *(uint2*)&aH[r * KP + kc * 4] = pk;
    }
  }
  // ---- stage wT: coalesced uint4 copy from pre-transposed wTg [144][KE]
  constexpr int WCH = 144 * KE / 8;   // 16B chunks
  for (int i = t; i < WCH; i += 256) {
    int c = i / (KE / 8), j = i % (KE / 8);
    *(uint4*)&wT[c * KP + j * 8] = *(const uint4*)&wTg[c * KE + j * 8];
  }
  __syncthreads();

  int w = t >> 6, l = t & 63;
  int cl = l & 15, r4 = l >> 4;
  int w16 = w * 16;

  f32x4 acc[9] = {};
#pragma unroll
  for (int ks = 0; ks < KE / 32; ks++) {
    f16x8 av = *(const f16x8*)&aH[(w16 + cl) * KP + ks * 32 + r4 * 8];
#pragma unroll
    for (int ct = 0; ct < 9; ct++) {
      f16x8 bv = *(const f16x8*)&wT[(ct * 16 + cl) * KP + ks * 32 + r4 * 8];
      acc[ct] = __builtin_amdgcn_mfma_f32_16x16x32_f16(av, bv, acc[ct], 0, 0, 0);
    }
  }

  // ---- scores: direct lane writes from tile 8 (cols 128..131)
#pragma unroll
  for (int i = 0; i < 4; i++) {
    int rloc = w16 + r4 * 4 + i;
    if (rloc < rows && cl < 4) {
      int row = node0 + rloc;
      float sv = acc[8][i];
      if (cl == 0) as_[row * 2] = sv;
      else if (cl == 1) as_[row * 2 + 1] = sv;
      else if (cl == 2) ad_[row * 2] = sv;
      else ad_[row * 2 + 1] = sv;
    }
  }

  __syncthreads();  // aH/wT dead -> reuse as hS
  // ---- C fragments -> hS fp16 [64][136]
#pragma unroll
  for (int ct = 0; ct < 8; ct++)
#pragma unroll
    for (int i = 0; i < 4; i++)
      hS[(w16 + r4 * 4 + i) * 136 + ct * 16 + cl] = __float2half(acc[ct][i]);
  __syncthreads();
  // ---- hS -> hb, coalesced 16B chunks (256B per node row)
#pragma unroll
  for (int it = 0; it < 4; it++) {
    int flat = t + it * 256;
    int nd = flat >> 4, ch = flat & 15;
    if (nd < rows)
      *(uint4*)((char*)hb + (((size_t)(node0 + nd)) << 8) + (ch << 4)) =
          *(const uint4*)((const char*)hS + nd * 272 + (ch << 4));
  }
}

// ---------------- GAT aggregation + fused BN stats --------------------------
// 16 lanes/node, 4 nodes/wave (R24 loop). Fused stats epilogue: per-wave
// shfl_xor(16/32) sum of o and o^2 (o already in registers), one barrier,
// plain stores to the block's PRIVATE slice stats[blockIdx*128] — no
// atomics, no fences. hb fp16 gathers; bufB fp16 NT stores.
__device__ __forceinline__ void fma8(float* a, float my, uint4 raw) {
  float2 f;
  f = __half22float2(__builtin_bit_cast(__half2, raw.x)); a[0] = fmaf(my, f.x, a[0]); a[1] = fmaf(my, f.y, a[1]);
  f = __half22float2(__builtin_bit_cast(__half2, raw.y)); a[2] = fmaf(my, f.x, a[2]); a[3] = fmaf(my, f.y, a[3]);
  f = __half22float2(__builtin_bit_cast(__half2, raw.z)); a[4] = fmaf(my, f.x, a[4]); a[5] = fmaf(my, f.y, a[5]);
  f = __half22float2(__builtin_bit_cast(__half2, raw.w)); a[6] = fmaf(my, f.x, a[6]); a[7] = fmaf(my, f.y, a[7]);
}

__global__ __launch_bounds__(256) void gat_aggregate(
    const __half2* __restrict__ hb,
    const float* __restrict__ as_, const float* __restrict__ ad_,
    const int* __restrict__ row_ptr, const int* __restrict__ col,
    const float* __restrict__ bias, __half* __restrict__ out,
    float* __restrict__ stats, int n) {
  __shared__ float ws[4][128];
  int t = threadIdx.x;
  int wv = t >> 6;
  int lane = t & 63;
  int g = lane >> 4, q = lane & 15;
  int d = blockIdx.x * 16 + wv * 4 + g;
  bool active = d < n;
  int hidx = (q >= 8) ? 1 : 0;
  const uint4* hb4 = (const uint4*)hb;   // 16 uint4 per node (256 B)

  float a[8] = {};
  float dpart = 0.f;

  if (active) {
    int beg = row_ptr[d], end = row_ptr[d + 1];
    float ad_my = ad_[d * 2 + hidx];

    // self-loop (not in CSR)
    float asv = as_[d * 2 + hidx];
    float my = __expf(leaky(asv + ad_my));
    uint4 raw = hb4[(size_t)d * 16 + q];
    fma8(a, my, raw);
    dpart = my;

    int k = beg;
    for (; k + 3 < end; k += 4) {
      int s0 = col[k], s1 = col[k + 1], s2 = col[k + 2], s3 = col[k + 3];
      float e0 = as_[s0 * 2 + hidx];
      float e1 = as_[s1 * 2 + hidx];
      float e2 = as_[s2 * 2 + hidx];
      float e3 = as_[s3 * 2 + hidx];
      uint4 r0 = hb4[(size_t)s0 * 16 + q];
      uint4 r1 = hb4[(size_t)s1 * 16 + q];
      uint4 r2 = hb4[(size_t)s2 * 16 + q];
      uint4 r3 = hb4[(size_t)s3 * 16 + q];
      float m0 = __expf(leaky(e0 + ad_my));
      float m1 = __expf(leaky(e1 + ad_my));
      float m2 = __expf(leaky(e2 + ad_my));
      float m3 = __expf(leaky(e3 + ad_my));
      fma8(a, m0, r0); fma8(a, m1, r1); fma8(a, m2, r2); fma8(a, m3, r3);
      dpart += m0 + m1 + m2 + m3;
    }
    for (; k < end; k++) {  // tail 0..3
      int s = col[k];
      float e = as_[s * 2 + hidx];
      uint4 r = hb4[(size_t)s * 16 + q];
      float m = __expf(leaky(e + ad_my));
      fma8(a, m, r);
      dpart += m;
    }
  }

  // head swap within the 16-lane group (serves all 4 nodes of the wave)
  float b[8];
#pragma unroll
  for (int i = 0; i < 8; i++) b[i] = __shfl_xor(a[i], 8);
  float denO = __shfl_xor(dpart, 8);

  float o[8] = {0.f, 0.f, 0.f, 0.f, 0.f, 0.f, 0.f, 0.f};
  if (active && q < 8) {  // channels 8q..8q+7
    float rr0 = 1.f / (dpart + 1e-16f), rr1 = 1.f / (denO + 1e-16f);
    float4 bl = *(const float4*)&bias[q * 8];
    float4 bh = *(const float4*)&bias[q * 8 + 4];
    o[0] = 0.5f * (a[0] * rr0 + b[0] * rr1) + bl.x;
    o[1] = 0.5f * (a[1] * rr0 + b[1] * rr1) + bl.y;
    o[2] = 0.5f * (a[2] * rr0 + b[2] * rr1) + bl.z;
    o[3] = 0.5f * (a[3] * rr0 + b[3] * rr1) + bl.w;
    o[4] = 0.5f * (a[4] * rr0 + b[4] * rr1) + bh.x;
    o[5] = 0.5f * (a[5] * rr0 + b[5] * rr1) + bh.y;
    o[6] = 0.5f * (a[6] * rr0 + b[6] * rr1) + bh.z;
    o[7] = 0.5f * (a[7] * rr0 + b[7] * rr1) + bh.w;
    u32x4 pk;
    pk.x = __builtin_bit_cast(unsigned, __floats2half2_rn(o[0], o[1]));
    pk.y = __builtin_bit_cast(unsigned, __floats2half2_rn(o[2], o[3]));
    pk.z = __builtin_bit_cast(unsigned, __floats2half2_rn(o[4], o[5]));
    pk.w = __builtin_bit_cast(unsigned, __floats2half2_rn(o[6], o[7]));
    u32x4* outp = (u32x4*)((char*)out + (((size_t)d) << 7) + (q << 4));
    __builtin_nontemporal_store(pk, outp);
  }

  // ---- fused BN stats: reduce this wave's 4 nodes via shfl (q>=8 and
  // inactive lanes carry zeros), then combine the block's 4 waves in LDS.
  float so[8], sq[8];
#pragma unroll
  for (int j = 0; j < 8; j++) {
    float v = o[j], v2 = o[j] * o[j];
    v += __shfl_xor(v, 16); v2 += __shfl_xor(v2, 16);
    v += __shfl_xor(v, 32); v2 += __shfl_xor(v2, 32);
    so[j] = v; sq[j] = v2;
  }
  if (lane < 8) {  // group-0 q<8 lanes hold the wave totals
#pragma unroll
    for (int j = 0; j < 8; j++) {
      ws[wv][lane * 8 + j] = so[j];
      ws[wv][64 + lane * 8 + j] = sq[j];
    }
  }
  __syncthreads();
  if (t < 128) {
    float s = ws[0][t] + ws[1][t] + ws[2][t] + ws[3][t];
    stats[(size_t)blockIdx.x * 128 + t] = s;
  }
}

// ---------------- MLP head: fused tiled GEMM (64 nodes / block) --------------
// a1 staging applies BN(layer3 scsh)+ReLU to the fp16 aggregate output.
// LDS 37.1 KB: GEMM1 output written IN-PLACE over a1, w2 over w1.
__global__ __launch_bounds__(256) void mlp_head_tiled(
    const __half* __restrict__ h3raw, const float* __restrict__ scsh,
    const float* __restrict__ x,
    const float* __restrict__ mW1, const float* __restrict__ mb1,
    const float* __restrict__ mW2, const float* __restrict__ mb2,
    const float* __restrict__ pW, const float* __restrict__ pb,
    const float* __restrict__ vW, const float* __restrict__ vb,
    float* __restrict__ out, int n) {
  __shared__ float lds[9280];
  float* a1  = lds;           // 64*68 = 4352; GEMM1 input, then GEMM1 output
  float* ctx = lds + 4352;    // 64*8  = 512
  float* w1  = lds + 4864;    // 69*64 = 4416; then w2 (64*64 = 4096)

  int t = threadIdx.x;
  int node0 = blockIdx.x * 64;
  int rows = min(64, n - node0);

#pragma unroll
  for (int i = 0; i < 2; i++) {
    int flat = t + i * 256;           // 64 rows x 8 chunks of 8 halves
    int r = flat >> 3, kc = flat & 7;
    uint4 hv = make_uint4(0, 0, 0, 0);
    if (r < rows) hv = *(const uint4*)(h3raw + (size_t)(node0 + r) * 64 + kc * 8);
    float2 f0 = __half22float2(__builtin_bit_cast(__half2, hv.x));
    float2 f1 = __half22float2(__builtin_bit_cast(__half2, hv.y));
    float2 f2 = __half22float2(__builtin_bit_cast(__half2, hv.z));
    float2 f3 = __half22float2(__builtin_bit_cast(__half2, hv.w));
    const float* sc = &scsh[kc * 8];
    const float* sh = &scsh[64 + kc * 8];
    float4 va, vb2;
    va.x = fmaxf(fmaf(f0.x, sc[0], sh[0]), 0.f);
    va.y = fmaxf(fmaf(f0.y, sc[1], sh[1]), 0.f);
    va.z = fmaxf(fmaf(f1.x, sc[2], sh[2]), 0.f);
    va.w = fmaxf(fmaf(f1.y, sc[3], sh[3]), 0.f);
    vb2.x = fmaxf(fmaf(f2.x, sc[4], sh[4]), 0.f);
    vb2.y = fmaxf(fmaf(f2.y, sc[5], sh[5]), 0.f);
    vb2.z = fmaxf(fmaf(f3.x, sc[6], sh[6]), 0.f);
    vb2.w = fmaxf(fmaf(f3.y, sc[7], sh[7]), 0.f);
    *(float4*)&a1[r * 68 + kc * 8] = va;
    *(float4*)&a1[r * 68 + kc * 8 + 4] = vb2;
  }
  for (int i = t; i < 320; i += 256) {
    int r = i / 5, j = i % 5;
    ctx[r * 8 + j] = (r < rows) ? x[(size_t)(node0 + r) * 16 + 9 + j] : 0.f;
  }
#pragma unroll
  for (int i = 0; i < 5; i++) {
    int flat = t + i * 256;
    if (flat < 1104) *(float4*)&w1[flat * 4] = *(const float4*)&mW1[flat * 4];
  }
  __syncthreads();

  int tc = t & 15, tr = t >> 4;
  int c0 = tc * 4, r0 = tr * 4;

  float acc[4][4] = {};
  for (int k = 0; k < 64; k += 4) {
    float4 av[4], wv[4];
#pragma unroll
    for (int i = 0; i < 4; i++) av[i] = *(const float4*)&a1[(r0 + i) * 68 + k];
#pragma unroll
    for (int j = 0; j < 4; j++) wv[j] = *(const float4*)&w1[(k + j) * 64 + c0];
#pragma unroll
    for (int i = 0; i < 4; i++) {
      const float* ai = (const float*)&av[i];
#pragma unroll
      for (int kk = 0; kk < 4; kk++) {
        const float* wr = (const float*)&wv[kk];
        acc[i][0] = fmaf(ai[kk], wr[0], acc[i][0]);
        acc[i][1] = fmaf(ai[kk], wr[1], acc[i][1]);
        acc[i][2] = fmaf(ai[kk], wr[2], acc[i][2]);
        acc[i][3] = fmaf(ai[kk], wr[3], acc[i][3]);
      }
    }
  }
#pragma unroll
  for (int k = 64; k < 69; k++) {
    float4 wv = *(const float4*)&w1[k * 64 + c0];
    const float* wr = (const float*)&wv;
#pragma unroll
    for (int i = 0; i < 4; i++) {
      float a = ctx[(r0 + i) * 8 + (k - 64)];
      acc[i][0] = fmaf(a, wr[0], acc[i][0]);
      acc[i][1] = fmaf(a, wr[1], acc[i][1]);
      acc[i][2] = fmaf(a, wr[2], acc[i][2]);
      acc[i][3] = fmaf(a, wr[3], acc[i][3]);
    }
  }
  float b1v0 = mb1[c0], b1v1 = mb1[c0 + 1], b1v2 = mb1[c0 + 2], b1v3 = mb1[c0 + 3];
  float4 t1v[4];
#pragma unroll
  for (int i = 0; i < 4; i++) {
    t1v[i].x = fmaxf(acc[i][0] + b1v0, 0.f);
    t1v[i].y = fmaxf(acc[i][1] + b1v1, 0.f);
    t1v[i].z = fmaxf(acc[i][2] + b1v2, 0.f);
    t1v[i].w = fmaxf(acc[i][3] + b1v3, 0.f);
  }
  __syncthreads();  // all GEMM1 reads of a1/w1 done -> regions reusable

  // GEMM1 output in-place over a1; w2 over w1
#pragma unroll
  for (int i = 0; i < 4; i++)
    *(float4*)&a1[(r0 + i) * 68 + c0] = t1v[i];
#pragma unroll
  for (int i = 0; i < 4; i++) {
    int flat = t + i * 256;
    *(float4*)&w1[flat * 4] = *(const float4*)&mW2[flat * 4];
  }
  __syncthreads();

  float acc2[4][4] = {};
  for (int k = 0; k < 64; k += 4) {
    float4 av[4], wv[4];
#pragma unroll
    for (int i = 0; i < 4; i++) av[i] = *(const float4*)&a1[(r0 + i) * 68 + k];
#pragma unroll
    for (int j = 0; j < 4; j++) wv[j] = *(const float4*)&w1[(k + j) * 64 + c0];
#pragma unroll
    for (int i = 0; i < 4; i++) {
      const float* ai = (const float*)&av[i];
#pragma unroll
      for (int kk = 0; kk < 4; kk++) {
        const float* wr = (const float*)&wv[kk];
        acc2[i][0] = fmaf(ai[kk], wr[0], acc2[i][0]);
        acc2[i][1] = fmaf(ai[kk], wr[1], acc2[i][1]);
        acc2[i][2] = fmaf(ai[kk], wr[2], acc2[i][2]);
        acc2[i][3] = fmaf(ai[kk], wr[3], acc2[i][3]);
      }
    }
  }

  float b2v[4], pwv[4], vwv[4];
#pragma unroll
  for (int j = 0; j < 4; j++) {
    b2v[j] = mb2[c0 + j];
    pwv[j] = pW[c0 + j];
    vwv[j] = vW[c0 + j];
  }
  float p[4], v[4];
#pragma unroll
  for (int i = 0; i < 4; i++) {
    float ps = 0.f, vs = 0.f;
#pragma unroll
    for (int j = 0; j < 4; j++) {
      float u = acc2[i][j] + b2v[j];
      ps = fmaf(u, pwv[j], ps);
      vs = fmaf(u, vwv[j], vs);
    }
    p[i] = ps; v[i] = vs;
  }
#pragma unroll
  for (int off = 1; off < 16; off <<= 1) {
#pragma unroll
    for (int i = 0; i < 4; i++) {
      p[i] += __shfl_xor(p[i], off);
      v[i] += __shfl_xor(v[i], off);
    }
  }
  if (tc == 0) {
    float pbs = pb[0], vbs = vb[0];
#pragma unroll
    for (int i = 0; i < 4; i++) {
      int r = r0 + i;
      if (r < rows) {
        out[node0 + r] = p[i] + pbs;
        out[n + node0 + r] = v[i] + vbs;
      }
    }
  }
}

extern "C" void kernel_launch(void* const* d_in, const int* in_sizes, int n_in,
                              void* d_out, int out_size, void* d_ws, size_t ws_size,
                              hipStream_t stream) {
  const float* x = (const float*)d_in[0];
  const int* ei = (const int*)d_in[1];
  const float* W[3]  = {(const float*)d_in[2],  (const float*)d_in[8],  (const float*)d_in[14]};
  const float* AS[3] = {(const float*)d_in[3],  (const float*)d_in[9],  (const float*)d_in[15]};
  const float* AD[3] = {(const float*)d_in[4],  (const float*)d_in[10], (const float*)d_in[16]};
  const float* B[3]  = {(const float*)d_in[5],  (const float*)d_in[11], (const float*)d_in[17]};
  const float* G[3]  = {(const float*)d_in[6],  (const float*)d_in[12], (const float*)d_in[18]};
  const float* BE[3] = {(const float*)d_in[7],  (const float*)d_in[13], (const float*)d_in[19]};
  const float* mW1 = (const float*)d_in[20];
  const float* mb1 = (const float*)d_in[21];
  const float* mW2 = (const float*)d_in[22];
  const float* mb2 = (const float*)d_in[23];
  const float* pW  = (const float*)d_in[24];
  const float* pb  = (const float*)d_in[25];
  const float* vW  = (const float*)d_in[26];
  const float* vb  = (const float*)d_in[27];

  const int N = in_sizes[0] / 16;
  const int E = in_sizes[1] / 2;
  const int* srcp = ei;
  const int* dstp = ei + E;

  const int agg_blocks = (N + 15) / 16;  // 4 nodes/wave, 4 waves/block

  // workspace carve-up (~63 MB)
  float* bufB  = (float*)d_ws;               // N*64 halves (fp16 activations)
  float* hbuf  = bufB + (size_t)N * 64;      // N*64 half2 region (fp16 hb)
  float* as_   = hbuf + (size_t)N * 64;      // N*2
  float* ad_   = as_ + (size_t)N * 2;        // N*2
  float* stats = ad_ + (size_t)N * 2;        // agg_blocks*128 (private slices)
  float* part  = stats + (size_t)agg_blocks * 128;  // 128*128 partials
  float* scsh  = part + 128 * 128;           // 128
  __half* wTg  = (__half*)(scsh + 128);      // 23040 halves (3 x [144][KE])
  int* row_ptr = (int*)(wTg + 23040);        // N+1
  int* bcnt    = row_ptr + (N + 1);          // 512
  int* boff    = bcnt + 512;                 // 512
  int* bcur    = boff + 512;                 // 512
  int* col     = bcur + 512;                 // E ints (sorted CSR, src only)
  int2* ebuf   = (int2*)(col + E);           // E int2 (staging)
  __half2* hb  = (__half2*)hbuf;
  __half* bufH = (__half*)bufB;
  const __half* wTgL[3] = {wTg, wTg + 4608, wTg + 13824};

  const int nbk = (N + 255) >> 8;
  const float inv_n = 1.0f / (float)N;

  // ---- W transposes + att precombine (once) + CSR build
  transpose_ws<<<90, 256, 0, stream>>>(W[0], W[1], W[2], AS[0], AD[0],
                                       AS[1], AD[1], AS[2], AD[2], wTg);
  hipMemsetAsync(bcnt, 0, sizeof(int) * 512, stream);
  bucket_hist<<<256, 256, 0, stream>>>(dstp, bcnt, E);
  bucket_scan<<<1, 512, 0, stream>>>(bcnt, boff, bcur, nbk);
  bin_scatter<<<(E + 8191) / 8192, 256, 0, stream>>>(srcp, dstp, bcur, ebuf, E);
  bucket_sort<<<nbk, 256, 0, stream>>>(ebuf, boff, col, row_ptr, E, N, nbk);

  const int tiles = (N + 63) / 64;

  // ---- 3 GAT layers (BN+ReLU fused into the next consumer via scsh;
  //      BN stats fused into aggregate; 2-stage parallel slice reduction)
  for (int l = 0; l < 3; l++) {
    if (l == 0)
      gat_project_mfma<16, false><<<tiles, 256, 0, stream>>>(x, scsh, wTgL[l],
                                                             hb, as_, ad_, N);
    else
      gat_project_mfma<64, true><<<tiles, 256, 0, stream>>>(bufH, scsh, wTgL[l],
                                                            hb, as_, ad_, N);
    gat_aggregate<<<agg_blocks, 256, 0, stream>>>(hb, as_, ad_, row_ptr, col,
                                                  B[l], bufH, stats, N);
    bn_reduce1<<<128, 256, 0, stream>>>(stats, part, agg_blocks);
    bn_finalize<<<1, 1024, 0, stream>>>(part, G[l], BE[l], scsh, inv_n);
  }

  // ---- MLP head -> (logits, value); applies layer-3 BN+ReLU to bufH
  mlp_head_tiled<<<tiles, 256, 0, stream>>>(bufH, scsh, x, mW1, mb1, mW2, mb2,
                                            pW, pb, vW, vb, (float*)d_out, N);
}